// Round 2
// baseline (532.371 us; speedup 1.0000x reference)
//
#include <hip/hip_runtime.h>

#define DEV static __device__ __forceinline__

typedef __attribute__((ext_vector_type(8))) __bf16 bf16x8;
typedef __attribute__((ext_vector_type(4))) float f32x4;
typedef __attribute__((ext_vector_type(4))) short short4v;  // v4i16 (4 bf16 bits)

constexpr int CB = 2;     // batch
constexpr int CS = 2048;  // seq
constexpr int CE = 1024;  // embed
constexpr int CH = 16;    // heads
constexpr int CD = 64;    // head dim

DEV unsigned short f2bf(float x) {  // RNE f32 -> bf16 bits
  unsigned int u = __float_as_uint(x);
  u += 0x7fffu + ((u >> 16) & 1u);
  return (unsigned short)(u >> 16);
}

DEV f32x4 mfma32(bf16x8 a, bf16x8 b, f32x4 c) {  // 16x16x32
  return __builtin_amdgcn_mfma_f32_16x16x32_bf16(a, b, c, 0, 0, 0);
}

DEV f32x4 mfma16(short4v a, short4v b, f32x4 c) {  // 16x16x16 (K=16)
#if __has_builtin(__builtin_amdgcn_mfma_f32_16x16x16bf16_1k)
  return __builtin_amdgcn_mfma_f32_16x16x16bf16_1k(a, b, c, 0, 0, 0);
#else
  f32x4 d;
  asm("v_mfma_f32_16x16x16_bf16 %0, %1, %2, %3" : "=v"(d) : "v"(a), "v"(b), "v"(c));
  return d;
#endif
}

DEV unsigned int cvtpk(float lo, float hi) {  // pack 2 f32 -> 2 bf16 (RNE)
  unsigned int r;
  asm("v_cvt_pk_bf16_f32 %0, %1, %2" : "=v"(r) : "v"(lo), "v"(hi));
  return r;
}

// ---------------- f32 -> bf16 convert (vectorized 8/thread) ----------------
__global__ __launch_bounds__(256) void cvt_bf16(const float* __restrict__ in,
                                                unsigned short* __restrict__ out, int n) {
  int i = (blockIdx.x * 256 + threadIdx.x) * 8;
  if (i >= n) return;
  float4 a = *reinterpret_cast<const float4*>(in + i);
  float4 b = *reinterpret_cast<const float4*>(in + i + 4);
  uint4 v;
  v.x = (unsigned int)f2bf(a.x) | ((unsigned int)f2bf(a.y) << 16);
  v.y = (unsigned int)f2bf(a.z) | ((unsigned int)f2bf(a.w) << 16);
  v.z = (unsigned int)f2bf(b.x) | ((unsigned int)f2bf(b.y) << 16);
  v.w = (unsigned int)f2bf(b.z) | ((unsigned int)f2bf(b.w) << 16);
  *reinterpret_cast<uint4*>(out + i) = v;
}

// ---------------- GEMM: C[M,N] = A[M,K] @ W[N,K]^T + bias[N] ----------------
// OM 0: bf16 row-major [M,N];  OM 1: f32 row-major;  OM 2: bf16 V^T [B,H,DK,S]
template<int OM>
__global__ __launch_bounds__(256) void gemm_bt(const unsigned short* __restrict__ A,
                                               const unsigned short* __restrict__ W,
                                               const float* __restrict__ bias,
                                               void* __restrict__ out,
                                               int M, int N, int K) {
  __shared__ __align__(16) unsigned short As[128][72];
  __shared__ __align__(16) unsigned short Bs[128][72];
  const int tid = threadIdx.x;
  const int lane = tid & 63, wave = tid >> 6;
  const int wm = (wave >> 1) * 64, wn = (wave & 1) * 64;
  const int g = lane >> 4, rr = lane & 15;
  const int m0 = blockIdx.x * 128, n0 = blockIdx.y * 128;
  f32x4 acc[4][4] = {};

  for (int k0 = 0; k0 < K; k0 += 64) {
#pragma unroll
    for (int t = 0; t < 4; t++) {
      const int cid = tid + t * 256;
      const int row = cid >> 3, col = (cid & 7) * 8;
      *reinterpret_cast<uint4*>(&As[row][col]) =
          *reinterpret_cast<const uint4*>(A + (long)(m0 + row) * K + k0 + col);
      *reinterpret_cast<uint4*>(&Bs[row][col]) =
          *reinterpret_cast<const uint4*>(W + (long)(n0 + row) * K + k0 + col);
    }
    __syncthreads();
#pragma unroll
    for (int kk = 0; kk < 2; kk++) {
      bf16x8 af[4], bfr[4];
#pragma unroll
      for (int i = 0; i < 4; i++)
        af[i] = *reinterpret_cast<const bf16x8*>(&As[wm + i * 16 + rr][kk * 32 + g * 8]);
#pragma unroll
      for (int j = 0; j < 4; j++)
        bfr[j] = *reinterpret_cast<const bf16x8*>(&Bs[wn + j * 16 + rr][kk * 32 + g * 8]);
#pragma unroll
      for (int i = 0; i < 4; i++)
#pragma unroll
        for (int j = 0; j < 4; j++)
          acc[i][j] = mfma32(af[i], bfr[j], acc[i][j]);
    }
    __syncthreads();
  }

#pragma unroll
  for (int i = 0; i < 4; i++) {
#pragma unroll
    for (int j = 0; j < 4; j++) {
      const int colg = n0 + wn + j * 16 + rr;
      const float bv = bias[colg];
      if (OM == 2) {
        const int rowbase = m0 + wm + i * 16 + g * 4;
        const int bb = rowbase >> 11, s = rowbase & 2047;
        const int hh = colg >> 6, d = colg & 63;
        uint2 val;
        val.x = (unsigned int)f2bf(acc[i][j][0] + bv) | ((unsigned int)f2bf(acc[i][j][1] + bv) << 16);
        val.y = (unsigned int)f2bf(acc[i][j][2] + bv) | ((unsigned int)f2bf(acc[i][j][3] + bv) << 16);
        *reinterpret_cast<uint2*>((unsigned short*)out +
                                  ((long)((bb * CH + hh) * CD + d)) * CS + s) = val;
      } else {
#pragma unroll
        for (int r = 0; r < 4; r++) {
          const int row = m0 + wm + i * 16 + g * 4 + r;
          const float v = acc[i][j][r] + bv;
          if (OM == 0) ((unsigned short*)out)[(long)row * N + colg] = f2bf(v);
          else         ((float*)out)[(long)row * N + colg] = v;
        }
      }
    }
  }
}

// ---------------- Flash attention, transposed-fragment form ----------------
// grid (S/64, H, B); 4 waves x 16 q-rows; KB=32 keys/iter. No LDS, no barriers.
// S^T = mfma(K, Q): lane holds k-slice for q = lane&15 -> lane-local softmax.
// O^T = mfma(V^T, P^T): P^T C-frag (k=g*4+r) IS the 16x16x16 B-frag layout.
__global__ __launch_bounds__(256, 4) void attn_kernel(const unsigned short* __restrict__ Qb,
                                                      const unsigned short* __restrict__ Kb,
                                                      const unsigned short* __restrict__ Vt,
                                                      const float* __restrict__ bias,
                                                      const int* __restrict__ mask,
                                                      unsigned short* __restrict__ AO) {
  const int qt = blockIdx.x, h = blockIdx.y, b = blockIdx.z;
  const int tid = threadIdx.x;
  const int lane = tid & 63, wave = tid >> 6;
  const int g = lane >> 4, c = lane & 15;
  const int q = qt * 64 + wave * 16 + c;  // this lane's query row

  // Q as B-frag: lane&15 = q-col, k(d) = g*8+j
  bf16x8 qf[2];
  {
    const unsigned short* Qrow = Qb + ((long)b * CS + q) * CE + h * CD;
#pragma unroll
    for (int kd = 0; kd < 2; kd++)
      qf[kd] = *reinterpret_cast<const bf16x8*>(Qrow + kd * 32 + g * 8);
  }
  const bool mq = mask[b * CS + q] != 0;
  const float* brow = bias + ((long)b * CS + q) * CS + g * 4;   // + kt + cb*16
  const int* mkp = mask + b * CS + g * 4;                        // + kt + cb*16
  const unsigned short* Kbase = Kb + (long)b * CS * CE + h * CD; // row = key idx
  const unsigned short* Vbase = Vt + (long)(b * CH + h) * CD * CS;

  f32x4 o[4] = {};  // O^T frags: nb -> d-block; row g*4+r = d_local, col c = q
  float mrun = -__builtin_inff(), lrun = 0.f;

  for (int kt = 0; kt < CS; kt += 32) {
    // ---- S^T = K @ Q^T : sf[cb] rows = k_local(cb*16+g*4+r), col = q(c) ----
    f32x4 sf[2] = {};
    bf16x8 kf[2][2];
#pragma unroll
    for (int kd = 0; kd < 2; kd++)
#pragma unroll
      for (int cb = 0; cb < 2; cb++)
        kf[kd][cb] = *reinterpret_cast<const bf16x8*>(
            Kbase + (long)(kt + cb * 16 + c) * CE + kd * 32 + g * 8);
    const int4 mk0 = *reinterpret_cast<const int4*>(mkp + kt);
    const int4 mk1 = *reinterpret_cast<const int4*>(mkp + kt + 16);
    const float4 bv0 = *reinterpret_cast<const float4*>(brow + kt);
    const float4 bv1 = *reinterpret_cast<const float4*>(brow + kt + 16);
#pragma unroll
    for (int kd = 0; kd < 2; kd++)
#pragma unroll
      for (int cb = 0; cb < 2; cb++)
        sf[cb] = mfma32(kf[kd][cb], qf[kd], sf[cb]);
    // V^T A-frags issued early: row = d(nb*16+c), k = cb*16+g*4+j (8B loads)
    uint2 vv[4][2];
#pragma unroll
    for (int nb = 0; nb < 4; nb++)
#pragma unroll
      for (int cb = 0; cb < 2; cb++)
        vv[nb][cb] = *reinterpret_cast<const uint2*>(
            Vbase + (long)(nb * 16 + c) * CS + kt + cb * 16 + g * 4);

    // ---- scores + mask (lane-local k-slice of 8 for query q) ----
    float pv[2][4];
    const int mks[2][4] = {{mk0.x, mk0.y, mk0.z, mk0.w}, {mk1.x, mk1.y, mk1.z, mk1.w}};
    const float bvs[2][4] = {{bv0.x, bv0.y, bv0.z, bv0.w}, {bv1.x, bv1.y, bv1.z, bv1.w}};
#pragma unroll
    for (int cb = 0; cb < 2; cb++)
#pragma unroll
      for (int r = 0; r < 4; r++)
        pv[cb][r] = (mq && mks[cb][r] != 0) ? fmaf(sf[cb][r], 0.125f, bvs[cb][r]) : -1e9f;

    // ---- online softmax: in-lane over 8, then xor-16/32 across g ----
    float tm = fmaxf(fmaxf(fmaxf(pv[0][0], pv[0][1]), fmaxf(pv[0][2], pv[0][3])),
                     fmaxf(fmaxf(pv[1][0], pv[1][1]), fmaxf(pv[1][2], pv[1][3])));
    tm = fmaxf(tm, __shfl_xor(tm, 16, 64));
    tm = fmaxf(tm, __shfl_xor(tm, 32, 64));
    const float nm = fmaxf(mrun, tm);
    const float scale = __expf(mrun - nm);
    mrun = nm;
    float p[2][4];
    float rs = 0.f;
#pragma unroll
    for (int cb = 0; cb < 2; cb++)
#pragma unroll
      for (int r = 0; r < 4; r++) {
        p[cb][r] = __expf(pv[cb][r] - nm);
        rs += p[cb][r];
      }
    rs += __shfl_xor(rs, 16, 64);
    rs += __shfl_xor(rs, 32, 64);
    lrun = fmaf(lrun, scale, rs);
#pragma unroll
    for (int nb = 0; nb < 4; nb++) {
      f32x4 t = o[nb];
#pragma unroll
      for (int r = 0; r < 4; r++) t[r] *= scale;
      o[nb] = t;
    }
    // ---- P^T -> bf16 B-frags (pure in-register) ----
    short4v pb[2];
#pragma unroll
    for (int cb = 0; cb < 2; cb++) {
      uint2 w;
      w.x = cvtpk(p[cb][0], p[cb][1]);
      w.y = cvtpk(p[cb][2], p[cb][3]);
      pb[cb] = __builtin_bit_cast(short4v, w);
    }
    // ---- O^T += V^T P^T ----
#pragma unroll
    for (int nb = 0; nb < 4; nb++)
#pragma unroll
      for (int cb = 0; cb < 2; cb++)
        o[nb] = mfma16(__builtin_bit_cast(short4v, vv[nb][cb]), pb[cb], o[nb]);
  }

  // ---- normalize + store: lane (g,c): row q, d = nb*16 + g*4 + r ----
  const float linv = 1.0f / lrun;
  unsigned short* Orow = AO + ((long)b * CS + q) * CE + h * CD;
#pragma unroll
  for (int nb = 0; nb < 4; nb++) {
    uint2 val;
    val.x = (unsigned int)f2bf(o[nb][0] * linv) | ((unsigned int)f2bf(o[nb][1] * linv) << 16);
    val.y = (unsigned int)f2bf(o[nb][2] * linv) | ((unsigned int)f2bf(o[nb][3] * linv) << 16);
    *reinterpret_cast<uint2*>(Orow + nb * 16 + g * 4) = val;
  }
}

// ---------------- host ----------------
extern "C" void kernel_launch(void* const* d_in, const int* in_sizes, int n_in,
                              void* d_out, int out_size, void* d_ws, size_t ws_size,
                              hipStream_t stream) {
  (void)in_sizes; (void)n_in; (void)out_size; (void)ws_size;
  const float* x    = (const float*)d_in[0];
  const float* kv   = (const float*)d_in[1];
  const int*   mask = (const int*)d_in[2];
  const float* ab   = (const float*)d_in[3];
  const float* WQw  = (const float*)d_in[4];
  const float* WQb  = (const float*)d_in[5];
  const float* WKw  = (const float*)d_in[6];
  const float* WKb  = (const float*)d_in[7];
  const float* WVw  = (const float*)d_in[8];
  const float* WVb  = (const float*)d_in[9];
  const float* WOw  = (const float*)d_in[10];
  const float* WOb  = (const float*)d_in[11];
  float* out = (float*)d_out;

  const long NE = (long)CB * CS * CE;  // 4,194,304
  const long WE = (long)CE * CE;       // 1,048,576
  unsigned short* ws  = (unsigned short*)d_ws;
  unsigned short* xb  = ws;
  unsigned short* kvb = xb + NE;
  unsigned short* wqb = kvb + NE;
  unsigned short* wkb = wqb + WE;
  unsigned short* wvb = wkb + WE;
  unsigned short* wob = wvb + WE;
  unsigned short* Qb  = wob + WE;
  unsigned short* Kb  = Qb + NE;
  unsigned short* Vt  = Kb + NE;   // [B,H,DK,S]
  unsigned short* AO  = Vt + NE;

  cvt_bf16<<<(int)(NE / 2048), 256, 0, stream>>>(x,   xb,  (int)NE);
  cvt_bf16<<<(int)(NE / 2048), 256, 0, stream>>>(kv,  kvb, (int)NE);
  cvt_bf16<<<(int)(WE / 2048), 256, 0, stream>>>(WQw, wqb, (int)WE);
  cvt_bf16<<<(int)(WE / 2048), 256, 0, stream>>>(WKw, wkb, (int)WE);
  cvt_bf16<<<(int)(WE / 2048), 256, 0, stream>>>(WVw, wvb, (int)WE);
  cvt_bf16<<<(int)(WE / 2048), 256, 0, stream>>>(WOw, wob, (int)WE);

  dim3 gg(32, 8, 1), gb(256, 1, 1);
  gemm_bt<0><<<gg, gb, 0, stream>>>(xb,  wqb, WQb, Qb,  CB * CS, CE, CE);
  gemm_bt<0><<<gg, gb, 0, stream>>>(kvb, wkb, WKb, Kb,  CB * CS, CE, CE);
  gemm_bt<2><<<gg, gb, 0, stream>>>(kvb, wvb, WVb, Vt,  CB * CS, CE, CE);

  attn_kernel<<<dim3(CS / 64, CH, CB), 256, 0, stream>>>(Qb, Kb, Vt, ab, mask, AO);

  gemm_bt<1><<<gg, gb, 0, stream>>>(AO, wob, WOb, out, CB * CS, CE, CE);
}

// Round 3
// 239.268 us; speedup vs baseline: 2.2250x; 2.2250x over previous
//
#include <hip/hip_runtime.h>

#define DEV static __device__ __forceinline__

typedef __attribute__((ext_vector_type(8))) __bf16 bf16x8;
typedef __attribute__((ext_vector_type(4))) float f32x4;
typedef __attribute__((ext_vector_type(4))) short short4v;

constexpr int CB = 2;     // batch
constexpr int CS = 2048;  // seq
constexpr int CE = 1024;  // embed
constexpr int CH = 16;    // heads
constexpr int CD = 64;    // head dim

DEV unsigned short f2bf(float x) {  // RNE f32 -> bf16 bits
  unsigned int u = __float_as_uint(x);
  u += 0x7fffu + ((u >> 16) & 1u);
  return (unsigned short)(u >> 16);
}

DEV f32x4 mfma32(bf16x8 a, bf16x8 b, f32x4 c) {  // 16x16x32
  return __builtin_amdgcn_mfma_f32_16x16x32_bf16(a, b, c, 0, 0, 0);
}

DEV f32x4 mfma16(short4v a, short4v b, f32x4 c) {  // 16x16x16 (K=16)
#if __has_builtin(__builtin_amdgcn_mfma_f32_16x16x16bf16_1k)
  return __builtin_amdgcn_mfma_f32_16x16x16bf16_1k(a, b, c, 0, 0, 0);
#else
  f32x4 d;
  asm("v_mfma_f32_16x16x16_bf16 %0, %1, %2, %3" : "=v"(d) : "v"(a), "v"(b), "v"(c));
  return d;
#endif
}

DEV unsigned int cvtpk(float lo, float hi) {  // pack 2 f32 -> 2 bf16 (RNE)
  unsigned int r;
  asm("v_cvt_pk_bf16_f32 %0, %1, %2" : "=v"(r) : "v"(lo), "v"(hi));
  return r;
}

DEV void stage16(const void* g, void* l) {  // async global(16B/lane) -> LDS
  __builtin_amdgcn_global_load_lds(
      (const __attribute__((address_space(1))) unsigned int*)g,
      (__attribute__((address_space(3))) unsigned int*)l, 16, 0, 0);
}

// ------- fused f32 -> bf16 convert: x | kv | WQ | WK | WV | WO -> contiguous ws -------
__global__ __launch_bounds__(256) void cvt_all(const float* __restrict__ x,
                                               const float* __restrict__ kv,
                                               const float* __restrict__ w0,
                                               const float* __restrict__ w1,
                                               const float* __restrict__ w2,
                                               const float* __restrict__ w3,
                                               unsigned short* __restrict__ out) {
  const long NE = (long)CB * CS * CE;  // 4 << 20
  const long WE = (long)CE * CE;       // 1 << 20
  long i = ((long)blockIdx.x * 256 + threadIdx.x) * 8;
  const float* src;
  long off = i;
  if (i < NE) {
    src = x;
  } else if (i < 2 * NE) {
    src = kv; off = i - NE;
  } else {
    long j = i - 2 * NE;
    int wi = (int)(j >> 20);
    src = wi == 0 ? w0 : wi == 1 ? w1 : wi == 2 ? w2 : w3;
    off = j & (WE - 1);
  }
  float4 a = *reinterpret_cast<const float4*>(src + off);
  float4 b = *reinterpret_cast<const float4*>(src + off + 4);
  uint4 v;
  v.x = (unsigned int)f2bf(a.x) | ((unsigned int)f2bf(a.y) << 16);
  v.y = (unsigned int)f2bf(a.z) | ((unsigned int)f2bf(a.w) << 16);
  v.z = (unsigned int)f2bf(b.x) | ((unsigned int)f2bf(b.y) << 16);
  v.w = (unsigned int)f2bf(b.z) | ((unsigned int)f2bf(b.w) << 16);
  *reinterpret_cast<uint4*>(out + i) = v;
}

// ---------------- GEMM (m97 structure): C = A[M,K] @ W[N,K]^T + bias, *scale ----------------
// OM 0: bf16 row-major [M,N];  OM 1: f32 row-major;  OM 2: bf16 V^T [B,H,DK,S]
template<int OM>
__global__ __launch_bounds__(256) void gemm_bt(const unsigned short* __restrict__ A,
                                               const unsigned short* __restrict__ W,
                                               const float* __restrict__ bias, float scale,
                                               void* __restrict__ out,
                                               int M, int N, int K) {
  __shared__ __align__(16) unsigned short As[128 * 64];  // linear: global_load_lds needs it
  __shared__ __align__(16) unsigned short Bs[128 * 64];
  const int tid = threadIdx.x;
  const int lane = tid & 63, wave = tid >> 6;
  const int wm = (wave >> 1) * 64, wn = (wave & 1) * 64;
  const int g = lane >> 4, rr = lane & 15;
  const int m0 = blockIdx.x * 128, n0 = blockIdx.y * 128;
  f32x4 acc[4][4] = {};

  for (int k0 = 0; k0 < K; k0 += 64) {
#pragma unroll
    for (int t = 0; t < 4; t++) {
      const int u = t * 256 + tid;
      const int row = u >> 3, ce = (u & 7) * 8;
      const int lb = (t * 256 + (tid & 192)) * 16;  // wave-uniform LDS byte base
      stage16(A + (long)(m0 + row) * K + k0 + ce, (char*)As + lb);
      stage16(W + (long)(n0 + row) * K + k0 + ce, (char*)Bs + lb);
    }
    __syncthreads();
#pragma unroll
    for (int kk = 0; kk < 2; kk++) {
      bf16x8 af[4], bfr[4];
#pragma unroll
      for (int i = 0; i < 4; i++)
        af[i] = *reinterpret_cast<const bf16x8*>(&As[(wm + i * 16 + rr) * 64 + kk * 32 + g * 8]);
#pragma unroll
      for (int j = 0; j < 4; j++)
        bfr[j] = *reinterpret_cast<const bf16x8*>(&Bs[(wn + j * 16 + rr) * 64 + kk * 32 + g * 8]);
#pragma unroll
      for (int i = 0; i < 4; i++)
#pragma unroll
        for (int j = 0; j < 4; j++)
          acc[i][j] = mfma32(af[i], bfr[j], acc[i][j]);
    }
    __syncthreads();
  }

#pragma unroll
  for (int i = 0; i < 4; i++) {
#pragma unroll
    for (int j = 0; j < 4; j++) {
      const int colg = n0 + wn + j * 16 + rr;
      const float bv = bias[colg];
      if (OM == 2) {
        const int rowbase = m0 + wm + i * 16 + g * 4;
        const int bb = rowbase >> 11, s = rowbase & 2047;
        const int hh = colg >> 6, d = colg & 63;
        uint2 val;
        val.x = (unsigned int)f2bf((acc[i][j][0] + bv) * scale) |
                ((unsigned int)f2bf((acc[i][j][1] + bv) * scale) << 16);
        val.y = (unsigned int)f2bf((acc[i][j][2] + bv) * scale) |
                ((unsigned int)f2bf((acc[i][j][3] + bv) * scale) << 16);
        *reinterpret_cast<uint2*>((unsigned short*)out +
                                  ((long)((bb * CH + hh) * CD + d)) * CS + s) = val;
      } else {
#pragma unroll
        for (int r = 0; r < 4; r++) {
          const int row = m0 + wm + i * 16 + g * 4 + r;
          const float v = (acc[i][j][r] + bv) * scale;
          if (OM == 0) ((unsigned short*)out)[(long)row * N + colg] = f2bf(v);
          else         ((float*)out)[(long)row * N + colg] = v;
        }
      }
    }
  }
}

// ---------------- Flash attention: LDS-staged K/V, lane-local softmax ----------------
// grid (S/64, H, B), 4 waves x 16 q. Per K-step(64): block stages K[64x64]+V^T[64x64]
// bf16 to LDS (global_load_lds, XOR-swizzled source), double-buffered.
// S^T = mfma(K,Q): lane owns k-slice of q=lane&15. P^T C-frag feeds PV B-frag directly.
__global__ __launch_bounds__(256) void attn_kernel(const unsigned short* __restrict__ Qb,
                                                   const unsigned short* __restrict__ Kb,
                                                   const unsigned short* __restrict__ Vtw,
                                                   const float* __restrict__ bias,
                                                   const int* __restrict__ mask,
                                                   unsigned short* __restrict__ AO) {
  __shared__ __align__(16) unsigned char lds[32768];  // 2 x (K 8KB | V 8KB)
  const int qt = blockIdx.x, h = blockIdx.y, b = blockIdx.z;
  const int tid = threadIdx.x;
  const int lane = tid & 63, w = tid >> 6;
  const int g = lane >> 4, c = lane & 15;
  const int q = qt * 64 + w * 16 + c;

  bf16x8 qf[2];  // B-frag: col=c=q, k(d)=kd*32+g*8+j  (Q pre-scaled by 1/8)
  {
    const unsigned short* Qrow = Qb + ((long)b * CS + q) * CE + h * CD;
    qf[0] = *reinterpret_cast<const bf16x8*>(Qrow + g * 8);
    qf[1] = *reinterpret_cast<const bf16x8*>(Qrow + 32 + g * 8);
  }
  const bool mq = mask[b * CS + q] != 0;
  const float* brow = bias + ((long)b * CS + q) * CS;
  const int* mrow = mask + b * CS;
  const unsigned char* Ksrc = (const unsigned char*)(Kb + (long)b * CS * CE + h * CD);
  const unsigned char* Vsrc = (const unsigned char*)(Vtw + (long)(b * CH + h) * CD * CS);

  f32x4 o[4] = {};
  float mrun = -__builtin_inff(), lrun = 0.f;

  auto stage = [&](unsigned char* buf, int kt) {
#pragma unroll
    for (int t = 0; t < 2; t++) {
      const int u = t * 256 + w * 64 + lane;
      const int row = u >> 3;                       // K: key_local / V: d
      const int cs = (u & 7) << 4;                  // swizzled LDS byte col
      const int csrc = cs ^ ((row & 7) << 4);       // inverse-swizzle the SOURCE
      stage16(Ksrc + (long)(kt + row) * (CE * 2) + csrc, buf + (t * 4 + w) * 1024);
      stage16(Vsrc + (long)row * (CS * 2) + kt * 2 + csrc, buf + 8192 + (t * 4 + w) * 1024);
    }
  };

  auto compute = [&](const unsigned char* buf, int kt) {
    // bias + key-mask loads (independent; issue early)
    float4 bv[4]; int4 mk[4];
#pragma unroll
    for (int cb = 0; cb < 4; cb++) {
      bv[cb] = *reinterpret_cast<const float4*>(brow + kt + cb * 16 + g * 4);
      mk[cb] = *reinterpret_cast<const int4*>(mrow + kt + cb * 16 + g * 4);
    }
    // S^T = K @ Q^T
    f32x4 sf[4] = {};
    const int sw = (c & 7) << 4;
#pragma unroll
    for (int cb = 0; cb < 4; cb++) {
      const int rowb = (cb * 16 + c) << 7;
#pragma unroll
      for (int kd = 0; kd < 2; kd++) {
        bf16x8 kf = *reinterpret_cast<const bf16x8*>(buf + rowb + ((kd * 64 + g * 16) ^ sw));
        sf[cb] = mfma32(kf, qf[kd], sf[cb]);
      }
    }
    // scores + mask; lane-local max over 16, then xor-16/32
    float p[4][4];
    float tm = -1e30f;
#pragma unroll
    for (int cb = 0; cb < 4; cb++) {
      const int mks[4] = {mk[cb].x, mk[cb].y, mk[cb].z, mk[cb].w};
      const float bvs[4] = {bv[cb].x, bv[cb].y, bv[cb].z, bv[cb].w};
#pragma unroll
      for (int r = 0; r < 4; r++) {
        const float s = (mq && mks[r] != 0) ? sf[cb][r] + bvs[r] : -1e9f;
        p[cb][r] = s;
        tm = fmaxf(tm, s);
      }
    }
    tm = fmaxf(tm, __shfl_xor(tm, 16, 64));
    tm = fmaxf(tm, __shfl_xor(tm, 32, 64));
    const float nm = fmaxf(mrun, tm);
    const float sc = __expf(mrun - nm);  // -inf on first tile -> 0
    mrun = nm;
    float rs = 0.f;
#pragma unroll
    for (int cb = 0; cb < 4; cb++)
#pragma unroll
      for (int r = 0; r < 4; r++) {
        p[cb][r] = __expf(p[cb][r] - nm);
        rs += p[cb][r];
      }
    rs += __shfl_xor(rs, 16, 64);
    rs += __shfl_xor(rs, 32, 64);
    lrun = fmaf(lrun, sc, rs);
#pragma unroll
    for (int nb = 0; nb < 4; nb++) {
      f32x4 t = o[nb];
#pragma unroll
      for (int r = 0; r < 4; r++) t[r] *= sc;
      o[nb] = t;
    }
    // P^T -> bf16 B-frags (in-register)
    short4v pb[4];
#pragma unroll
    for (int cb = 0; cb < 4; cb++) {
      uint2 t;
      t.x = cvtpk(p[cb][0], p[cb][1]);
      t.y = cvtpk(p[cb][2], p[cb][3]);
      pb[cb] = __builtin_bit_cast(short4v, t);
    }
    // O^T += V^T P^T
#pragma unroll
    for (int nb = 0; nb < 4; nb++) {
      const int rowb = 8192 + ((nb * 16 + c) << 7);
#pragma unroll
      for (int cb = 0; cb < 4; cb++) {
        const uint2 vv = *reinterpret_cast<const uint2*>(buf + rowb + ((cb * 32 + g * 8) ^ sw));
        o[nb] = mfma16(__builtin_bit_cast(short4v, vv), pb[cb], o[nb]);
      }
    }
  };

  unsigned char* buf0 = lds;
  unsigned char* buf1 = lds + 16384;
  stage(buf0, 0);
  __syncthreads();
#pragma unroll 1
  for (int kt = 0; kt < CS; kt += 128) {
    stage(buf1, kt + 64);
    compute(buf0, kt);
    __syncthreads();
    if (kt + 128 < CS) stage(buf0, kt + 128);
    compute(buf1, kt + 64);
    __syncthreads();
  }

  const float linv = 1.0f / lrun;
  unsigned short* Orow = AO + ((long)b * CS + q) * CE + h * CD;
#pragma unroll
  for (int nb = 0; nb < 4; nb++) {
    uint2 val;
    val.x = (unsigned int)f2bf(o[nb][0] * linv) | ((unsigned int)f2bf(o[nb][1] * linv) << 16);
    val.y = (unsigned int)f2bf(o[nb][2] * linv) | ((unsigned int)f2bf(o[nb][3] * linv) << 16);
    *reinterpret_cast<uint2*>(Orow + nb * 16 + g * 4) = val;
  }
}

// ---------------- host ----------------
extern "C" void kernel_launch(void* const* d_in, const int* in_sizes, int n_in,
                              void* d_out, int out_size, void* d_ws, size_t ws_size,
                              hipStream_t stream) {
  (void)in_sizes; (void)n_in; (void)out_size; (void)ws_size;
  const float* x    = (const float*)d_in[0];
  const float* kv   = (const float*)d_in[1];
  const int*   mask = (const int*)d_in[2];
  const float* ab   = (const float*)d_in[3];
  const float* WQw  = (const float*)d_in[4];
  const float* WQb  = (const float*)d_in[5];
  const float* WKw  = (const float*)d_in[6];
  const float* WKb  = (const float*)d_in[7];
  const float* WVw  = (const float*)d_in[8];
  const float* WVb  = (const float*)d_in[9];
  const float* WOw  = (const float*)d_in[10];
  const float* WOb  = (const float*)d_in[11];
  float* out = (float*)d_out;

  const long NE = (long)CB * CS * CE;  // 4,194,304
  const long WE = (long)CE * CE;       // 1,048,576
  unsigned short* ws  = (unsigned short*)d_ws;
  unsigned short* xb  = ws;            // [x | kv | WQ | WK | WV | WO] contiguous
  unsigned short* kvb = xb + NE;
  unsigned short* wqb = kvb + NE;
  unsigned short* wkb = wqb + WE;
  unsigned short* wvb = wkb + WE;
  unsigned short* wob = wvb + WE;
  unsigned short* Qb  = wob + WE;
  unsigned short* Kb  = Qb + NE;
  unsigned short* Vt  = Kb + NE;   // [B,H,DK,S]
  unsigned short* AO  = Vt + NE;

  const long TOT = 2 * NE + 4 * WE;  // 12,582,912
  cvt_all<<<(int)(TOT / 2048), 256, 0, stream>>>(x, kv, WQw, WKw, WVw, WOw, xb);

  dim3 gg(32, 8, 1), gb(256, 1, 1);
  gemm_bt<0><<<gg, gb, 0, stream>>>(xb,  wqb, WQb, 0.125f, Qb, CB * CS, CE, CE);  // 1/sqrt(dk) folded
  gemm_bt<0><<<gg, gb, 0, stream>>>(kvb, wkb, WKb, 1.0f,   Kb, CB * CS, CE, CE);
  gemm_bt<2><<<gg, gb, 0, stream>>>(kvb, wvb, WVb, 1.0f,   Vt, CB * CS, CE, CE);

  attn_kernel<<<dim3(CS / 64, CH, CB), 256, 0, stream>>>(Qb, Kb, Vt, ab, mask, AO);

  gemm_bt<1><<<gg, gb, 0, stream>>>(AO, wob, WOb, 1.0f, out, CB * CS, CE, CE);
}

// Round 4
// 195.812 us; speedup vs baseline: 2.7188x; 1.2219x over previous
//
#include <hip/hip_runtime.h>

#define DEV static __device__ __forceinline__

typedef __attribute__((ext_vector_type(8))) __bf16 bf16x8;
typedef __attribute__((ext_vector_type(4))) float f32x4;

constexpr int CB = 2;     // batch
constexpr int CS = 2048;  // seq
constexpr int CE = 1024;  // embed
constexpr int CH = 16;    // heads
constexpr int CD = 64;    // head dim
constexpr float LOG2E = 1.44269504f;

DEV unsigned short f2bf(float x) {  // RNE f32 -> bf16 bits
  unsigned int u = __float_as_uint(x);
  u += 0x7fffu + ((u >> 16) & 1u);
  return (unsigned short)(u >> 16);
}

DEV f32x4 mfma32(bf16x8 a, bf16x8 b, f32x4 c) {  // 16x16x32
  return __builtin_amdgcn_mfma_f32_16x16x32_bf16(a, b, c, 0, 0, 0);
}

DEV unsigned int cvtpk(float lo, float hi) {  // pack 2 f32 -> 2 bf16 (RNE)
  unsigned int r;
  asm("v_cvt_pk_bf16_f32 %0, %1, %2" : "=v"(r) : "v"(lo), "v"(hi));
  return r;
}

DEV void stage16(const void* g, void* l) {  // async global(16B/lane) -> LDS
  __builtin_amdgcn_global_load_lds(
      (const __attribute__((address_space(1))) unsigned int*)g,
      (__attribute__((address_space(3))) unsigned int*)l, 16, 0, 0);
}

// ------- fused f32 -> bf16 convert: x | kv | WQ | WK | WV | WO -> contiguous ws -------
__global__ __launch_bounds__(256) void cvt_all(const float* __restrict__ x,
                                               const float* __restrict__ kv,
                                               const float* __restrict__ w0,
                                               const float* __restrict__ w1,
                                               const float* __restrict__ w2,
                                               const float* __restrict__ w3,
                                               unsigned short* __restrict__ out) {
  const long NE = (long)CB * CS * CE;
  const long WE = (long)CE * CE;
  long i = ((long)blockIdx.x * 256 + threadIdx.x) * 8;
  const float* src;
  long off = i;
  if (i < NE) {
    src = x;
  } else if (i < 2 * NE) {
    src = kv; off = i - NE;
  } else {
    long j = i - 2 * NE;
    int wi = (int)(j >> 20);
    src = wi == 0 ? w0 : wi == 1 ? w1 : wi == 2 ? w2 : w3;
    off = j & (WE - 1);
  }
  float4 a = *reinterpret_cast<const float4*>(src + off);
  float4 b = *reinterpret_cast<const float4*>(src + off + 4);
  uint4 v;
  v.x = (unsigned int)f2bf(a.x) | ((unsigned int)f2bf(a.y) << 16);
  v.y = (unsigned int)f2bf(a.z) | ((unsigned int)f2bf(a.w) << 16);
  v.z = (unsigned int)f2bf(b.x) | ((unsigned int)f2bf(b.y) << 16);
  v.w = (unsigned int)f2bf(b.z) | ((unsigned int)f2bf(b.w) << 16);
  *reinterpret_cast<uint4*>(out + i) = v;
}

// ---------------- fused QKV GEMM: [Q|K|V] = A @ W{q,k,v}^T + bias ----------------
// grid (M/128, 24): blockIdx.y selects matrix (8 n-blocks each). m97 structure.
__global__ __launch_bounds__(256) void gemm_qkv(const unsigned short* __restrict__ xb,
                                                const unsigned short* __restrict__ kvb,
                                                const unsigned short* __restrict__ Wall,
                                                const float* __restrict__ bq,
                                                const float* __restrict__ bk,
                                                const float* __restrict__ bv,
                                                unsigned short* __restrict__ Qb) {
  __shared__ __align__(16) unsigned short As[128 * 64];
  __shared__ __align__(16) unsigned short Bs[128 * 64];
  const long NE = (long)CB * CS * CE;
  const long WE = (long)CE * CE;
  const int which = blockIdx.y >> 3;           // 0=Q 1=K 2=V
  const int n0 = (blockIdx.y & 7) * 128;
  const unsigned short* A = which == 0 ? xb : kvb;
  const unsigned short* W = Wall + (long)which * WE;
  const float* bias = which == 0 ? bq : which == 1 ? bk : bv;
  const int tid = threadIdx.x;
  const int lane = tid & 63, wave = tid >> 6;
  const int wm = (wave >> 1) * 64, wn = (wave & 1) * 64;
  const int g = lane >> 4, rr = lane & 15;
  const int m0 = blockIdx.x * 128;
  const int K = CE;
  f32x4 acc[4][4] = {};

  for (int k0 = 0; k0 < K; k0 += 64) {
#pragma unroll
    for (int t = 0; t < 4; t++) {
      const int u = t * 256 + tid;
      const int row = u >> 3, ce = (u & 7) * 8;
      const int lb = (t * 256 + (tid & 192)) * 16;
      stage16(A + (long)(m0 + row) * K + k0 + ce, (char*)As + lb);
      stage16(W + (long)(n0 + row) * K + k0 + ce, (char*)Bs + lb);
    }
    __syncthreads();
#pragma unroll
    for (int kk = 0; kk < 2; kk++) {
      bf16x8 af[4], bfr[4];
#pragma unroll
      for (int i = 0; i < 4; i++)
        af[i] = *reinterpret_cast<const bf16x8*>(&As[(wm + i * 16 + rr) * 64 + kk * 32 + g * 8]);
#pragma unroll
      for (int j = 0; j < 4; j++)
        bfr[j] = *reinterpret_cast<const bf16x8*>(&Bs[(wn + j * 16 + rr) * 64 + kk * 32 + g * 8]);
#pragma unroll
      for (int i = 0; i < 4; i++)
#pragma unroll
        for (int j = 0; j < 4; j++)
          acc[i][j] = mfma32(af[i], bfr[j], acc[i][j]);
    }
    __syncthreads();
  }

  const float scale = which == 0 ? 0.125f * LOG2E : 1.0f;  // fold 1/sqrt(dk)*log2e into Q
#pragma unroll
  for (int i = 0; i < 4; i++) {
#pragma unroll
    for (int j = 0; j < 4; j++) {
      const int colg = n0 + wn + j * 16 + rr;
      const float bvv = bias[colg];
      if (which == 2) {  // V^T layout [B,H,DK,S]
        const int rowbase = m0 + wm + i * 16 + g * 4;
        const int bb = rowbase >> 11, s = rowbase & 2047;
        const int hh = colg >> 6, d = colg & 63;
        uint2 val;
        val.x = (unsigned int)f2bf(acc[i][j][0] + bvv) | ((unsigned int)f2bf(acc[i][j][1] + bvv) << 16);
        val.y = (unsigned int)f2bf(acc[i][j][2] + bvv) | ((unsigned int)f2bf(acc[i][j][3] + bvv) << 16);
        *reinterpret_cast<uint2*>(Qb + 2 * NE + ((long)((bb * CH + hh) * CD + d)) * CS + s) = val;
      } else {
        unsigned short* outp = Qb + (long)which * NE;
#pragma unroll
        for (int r = 0; r < 4; r++) {
          const int row = m0 + wm + i * 16 + g * 4 + r;
          outp[(long)row * CE + colg] = f2bf((acc[i][j][r] + bvv) * scale);
        }
      }
    }
  }
}

// ---------------- WO GEMM: out_f32 = A @ W^T + bias ----------------
__global__ __launch_bounds__(256) void gemm_wo(const unsigned short* __restrict__ A,
                                               const unsigned short* __restrict__ W,
                                               const float* __restrict__ bias,
                                               float* __restrict__ out) {
  __shared__ __align__(16) unsigned short As[128 * 64];
  __shared__ __align__(16) unsigned short Bs[128 * 64];
  const int tid = threadIdx.x;
  const int lane = tid & 63, wave = tid >> 6;
  const int wm = (wave >> 1) * 64, wn = (wave & 1) * 64;
  const int g = lane >> 4, rr = lane & 15;
  const int m0 = blockIdx.x * 128, n0 = blockIdx.y * 128;
  const int K = CE;
  f32x4 acc[4][4] = {};

  for (int k0 = 0; k0 < K; k0 += 64) {
#pragma unroll
    for (int t = 0; t < 4; t++) {
      const int u = t * 256 + tid;
      const int row = u >> 3, ce = (u & 7) * 8;
      const int lb = (t * 256 + (tid & 192)) * 16;
      stage16(A + (long)(m0 + row) * K + k0 + ce, (char*)As + lb);
      stage16(W + (long)(n0 + row) * K + k0 + ce, (char*)Bs + lb);
    }
    __syncthreads();
#pragma unroll
    for (int kk = 0; kk < 2; kk++) {
      bf16x8 af[4], bfr[4];
#pragma unroll
      for (int i = 0; i < 4; i++)
        af[i] = *reinterpret_cast<const bf16x8*>(&As[(wm + i * 16 + rr) * 64 + kk * 32 + g * 8]);
#pragma unroll
      for (int j = 0; j < 4; j++)
        bfr[j] = *reinterpret_cast<const bf16x8*>(&Bs[(wn + j * 16 + rr) * 64 + kk * 32 + g * 8]);
#pragma unroll
      for (int i = 0; i < 4; i++)
#pragma unroll
        for (int j = 0; j < 4; j++)
          acc[i][j] = mfma32(af[i], bfr[j], acc[i][j]);
    }
    __syncthreads();
  }

#pragma unroll
  for (int i = 0; i < 4; i++)
#pragma unroll
    for (int j = 0; j < 4; j++) {
      const int colg = n0 + wn + j * 16 + rr;
      const float bvv = bias[colg];
#pragma unroll
      for (int r = 0; r < 4; r++) {
        const int row = m0 + wm + i * 16 + g * 4 + r;
        out[(long)row * CE + colg] = acc[i][j][r] + bvv;
      }
    }
}

// ---------------- Flash attention v3 ----------------
// grid (S/64, H, B), 4 waves x 16 q. K staged PERMUTED: key 8g+j -> LDS row
// (j>>2)*16+4g+(j&3), so the S^T C-frag per-lane k-set = mfma32 B-frag layout
// after cvt_pk (PV = 8x mfma32, V read b128 conflict-free). Bias+mask pre-
// fetched 1 tile ahead, fused to mbias = MFMA C-init. Defer-max: common path
// has zero cross-lane ops; lsum g-reduced once at end. exp2 domain.
__global__ __launch_bounds__(256) void attn_kernel(const unsigned short* __restrict__ Qb,
                                                   const unsigned short* __restrict__ Kb,
                                                   const unsigned short* __restrict__ Vtw,
                                                   const float* __restrict__ bias,
                                                   const int* __restrict__ mask,
                                                   unsigned short* __restrict__ AO) {
  __shared__ __align__(16) unsigned char lds[32768];  // 2 x (K 8KB | V 8KB)
  const int qt = blockIdx.x, h = blockIdx.y, b = blockIdx.z;
  const int tid = threadIdx.x;
  const int lane = tid & 63, w = tid >> 6;
  const int g = lane >> 4, c = lane & 15;
  const int q = qt * 64 + w * 16 + c;

  const bool mq = mask[b * CS + q] != 0;
  bf16x8 qf[2];  // B-frag: col=c=q, k(d)=kd*32+g*8+j  (Q pre-scaled 0.125*log2e)
  {
    const unsigned short* Qrow = Qb + ((long)b * CS + q) * CE + h * CD;
    qf[0] = *reinterpret_cast<const bf16x8*>(Qrow + g * 8);
    qf[1] = *reinterpret_cast<const bf16x8*>(Qrow + 32 + g * 8);
    if (!mq) { qf[0] = bf16x8{}; qf[1] = bf16x8{}; }  // exact-uniform masked rows
  }
  const float* brow = bias + ((long)b * CS + q) * CS;
  const int* mrow = mask + b * CS;
  const unsigned char* Ksrc = (const unsigned char*)(Kb + (long)b * CS * CE + h * CD);
  const unsigned char* Vsrc = (const unsigned char*)(Vtw + (long)(b * CH + h) * CD * CS);

  f32x4 o[4] = {};
  float mrun = -__builtin_inff(), lsum = 0.f;

  // stage K (row-permuted) + V into LDS buffer
  auto stage = [&](unsigned char* buf, int kt) {
#pragma unroll
    for (int t = 0; t < 2; t++) {
      const int rowp = t * 32 + w * 8 + (lane >> 3);  // LDS row 0..63
      const int cs = (lane & 7) << 4;
      const int csrc = cs ^ ((rowp & 7) << 4);        // inverse-swizzle SOURCE
      const int key = (rowp & 32) + ((rowp >> 2) & 3) * 8 + ((rowp >> 4) & 1) * 4 + (rowp & 3);
      stage16(Ksrc + (long)(kt + key) * (CE * 2) + csrc, buf + (t * 4 + w) * 1024);
      stage16(Vsrc + (long)rowp * (CS * 2) + (long)kt * 2 + csrc, buf + 8192 + (t * 4 + w) * 1024);
    }
  };
  // prefetch bias+mask for tile kt, fused: mbias = (mq&&mk)? bias*log2e : -1e9
  auto load_mb = [&](f32x4* d, int kt) {
#pragma unroll
    for (int cb = 0; cb < 4; cb++) {
      const int off = kt + ((cb >> 1) << 5) + ((cb & 1) << 2) + g * 8;  // permuted key base
      const float4 bv = *reinterpret_cast<const float4*>(brow + off);
      const int4 mk = *reinterpret_cast<const int4*>(mrow + off);
      f32x4 m;
      m[0] = (mq && mk.x != 0) ? bv.x * LOG2E : -1e9f;
      m[1] = (mq && mk.y != 0) ? bv.y * LOG2E : -1e9f;
      m[2] = (mq && mk.z != 0) ? bv.z * LOG2E : -1e9f;
      m[3] = (mq && mk.w != 0) ? bv.w * LOG2E : -1e9f;
      d[cb] = m;
    }
  };

  f32x4 mbr[4];
  stage(lds, 0);
  load_mb(mbr, 0);
  __syncthreads();

  const int sw = (c & 7) << 4;
#pragma unroll 1
  for (int kt = 0; kt < CS; kt += 64) {
    const int pp = (kt >> 6) & 1;
    const unsigned char* cur = lds + pp * 16384;
    unsigned char* nxt = lds + (pp ^ 1) * 16384;
    f32x4 mbn[4];
    const bool more = kt + 64 < CS;
    if (more) {
      stage(nxt, kt + 64);
      load_mb(mbn, kt + 64);
    }
    // ---- S^T: C-init = mbias, += K @ Q^T ----
    f32x4 sf[4];
#pragma unroll
    for (int cb = 0; cb < 4; cb++) {
      sf[cb] = mbr[cb];
      const int rowb = (cb * 16 + c) << 7;
#pragma unroll
      for (int kd = 0; kd < 2; kd++) {
        const bf16x8 kf = *reinterpret_cast<const bf16x8*>(cur + rowb + ((kd * 64 + g * 16) ^ sw));
        sf[cb] = mfma32(kf, qf[kd], sf[cb]);
      }
    }
    // ---- online softmax, defer-max (log2 domain) ----
    float ltm = fmaxf(fmaxf(fmaxf(sf[0][0], sf[0][1]), fmaxf(sf[0][2], sf[0][3])),
                      fmaxf(fmaxf(sf[1][0], sf[1][1]), fmaxf(sf[1][2], sf[1][3])));
    ltm = fmaxf(ltm, fmaxf(fmaxf(fmaxf(sf[2][0], sf[2][1]), fmaxf(sf[2][2], sf[2][3])),
                           fmaxf(fmaxf(sf[3][0], sf[3][1]), fmaxf(sf[3][2], sf[3][3]))));
    if (!__all(ltm <= mrun + 8.0f)) {
      float tm = fmaxf(ltm, __shfl_xor(ltm, 16, 64));
      tm = fmaxf(tm, __shfl_xor(tm, 32, 64));
      const float nm = fmaxf(mrun, tm);
      const float scf = exp2f(mrun - nm);  // -inf first tile -> 0
      mrun = nm;
      lsum *= scf;
#pragma unroll
      for (int nb = 0; nb < 4; nb++) {
        f32x4 t = o[nb];
#pragma unroll
        for (int r = 0; r < 4; r++) t[r] *= scf;
        o[nb] = t;
      }
    }
    float p[4][4];
#pragma unroll
    for (int cb = 0; cb < 4; cb++)
#pragma unroll
      for (int r = 0; r < 4; r++) {
        p[cb][r] = exp2f(sf[cb][r] - mrun);
        lsum += p[cb][r];
      }
    // ---- P -> mfma32 B-frags (pure in-register; k = kb*32 + g*8 + j) ----
    uint4 pw[2];
#pragma unroll
    for (int kb = 0; kb < 2; kb++) {
      pw[kb].x = cvtpk(p[2 * kb][0], p[2 * kb][1]);
      pw[kb].y = cvtpk(p[2 * kb][2], p[2 * kb][3]);
      pw[kb].z = cvtpk(p[2 * kb + 1][0], p[2 * kb + 1][1]);
      pw[kb].w = cvtpk(p[2 * kb + 1][2], p[2 * kb + 1][3]);
    }
    // ---- O^T += V^T P^T (b128 V reads, conflict-free) ----
#pragma unroll
    for (int nb = 0; nb < 4; nb++) {
      const int rowb = 8192 + ((nb * 16 + c) << 7);
#pragma unroll
      for (int kb = 0; kb < 2; kb++) {
        const bf16x8 vf = *reinterpret_cast<const bf16x8*>(cur + rowb + ((kb * 64 + g * 16) ^ sw));
        o[nb] = mfma32(vf, __builtin_bit_cast(bf16x8, pw[kb]), o[nb]);
      }
    }
    __syncthreads();
    if (more) {
#pragma unroll
      for (int cb = 0; cb < 4; cb++) mbr[cb] = mbn[cb];
    }
  }

  lsum += __shfl_xor(lsum, 16, 64);
  lsum += __shfl_xor(lsum, 32, 64);
  const float linv = 1.0f / lsum;
  unsigned short* Orow = AO + ((long)b * CS + q) * CE + h * CD;
#pragma unroll
  for (int nb = 0; nb < 4; nb++) {
    uint2 val;
    val.x = (unsigned int)f2bf(o[nb][0] * linv) | ((unsigned int)f2bf(o[nb][1] * linv) << 16);
    val.y = (unsigned int)f2bf(o[nb][2] * linv) | ((unsigned int)f2bf(o[nb][3] * linv) << 16);
    *reinterpret_cast<uint2*>(Orow + nb * 16 + g * 4) = val;
  }
}

// ---------------- host ----------------
extern "C" void kernel_launch(void* const* d_in, const int* in_sizes, int n_in,
                              void* d_out, int out_size, void* d_ws, size_t ws_size,
                              hipStream_t stream) {
  (void)in_sizes; (void)n_in; (void)out_size; (void)ws_size;
  const float* x    = (const float*)d_in[0];
  const float* kv   = (const float*)d_in[1];
  const int*   mask = (const int*)d_in[2];
  const float* ab   = (const float*)d_in[3];
  const float* WQw  = (const float*)d_in[4];
  const float* WQb  = (const float*)d_in[5];
  const float* WKw  = (const float*)d_in[6];
  const float* WKb  = (const float*)d_in[7];
  const float* WVw  = (const float*)d_in[8];
  const float* WVb  = (const float*)d_in[9];
  const float* WOw  = (const float*)d_in[10];
  const float* WOb  = (const float*)d_in[11];
  float* out = (float*)d_out;

  const long NE = (long)CB * CS * CE;  // 4,194,304
  const long WE = (long)CE * CE;       // 1,048,576
  unsigned short* ws  = (unsigned short*)d_ws;
  unsigned short* xb  = ws;            // [x | kv | WQ | WK | WV | WO] contiguous
  unsigned short* kvb = xb + NE;
  unsigned short* wqb = kvb + NE;      // WQ|WK|WV contiguous = Wall
  unsigned short* wob = wqb + 3 * WE;
  unsigned short* Qb  = wob + WE;      // Q | K | Vt contiguous
  unsigned short* AO  = Qb + 3 * NE;

  const long TOT = 2 * NE + 4 * WE;
  cvt_all<<<(int)(TOT / 2048), 256, 0, stream>>>(x, kv, WQw, WKw, WVw, WOw, xb);

  gemm_qkv<<<dim3(32, 24), 256, 0, stream>>>(xb, kvb, wqb, WQb, WKb, WVb, Qb);

  attn_kernel<<<dim3(CS / 64, CH, CB), 256, 0, stream>>>(
      Qb, Qb + NE, Qb + 2 * NE, ab, mask, AO);

  gemm_wo<<<dim3(32, 8), 256, 0, stream>>>(AO, wob, WOb, out);
}